// Round 12
// baseline (537.305 us; speedup 1.0000x reference)
//
#include <hip/hip_runtime.h>
#include <hip/hip_bf16.h>
#include <math.h>

#define N_NODES   100000
#define N_EDGES   3200000
#define IN_DIM    128
#define HID       64
#define OUT_DIM   10
#define N_GRAPHS  64

// Radix geometry: bucket = row >> 8 (256 rows/bucket), tile = 8192 edges.
// etmp records are 4 B (rowLocal<<24 | edgeIdx) -> half the scatter bytes
// of R11; cols/vals are re-gathered in bucket_sort from mostly-sequential
// 32 KB windows (runs are tile-ordered within a bucket).
#define BUCKET_SHIFT 8
#define BUCKET_ROWS  256
#define NBUCKET ((N_NODES + BUCKET_ROWS - 1) >> BUCKET_SHIFT)     // 391
#define TILE_EDGES 8192                                           // 1024 thr x 8
#define NTILES ((N_EDGES + TILE_EDGES - 1) / TILE_EDGES)          // 391
#define NH (NBUCKET * NTILES)                                     // 152,881
#define NSCAN1 ((NH + 1023) / 1024)                               // 150
#define EPAD (N_EDGES + 7 * NH)                                   // max padded slots

#define SENT4 0xFFFFFFFFu    // idx bits = 0xFFFFFF (> N_EDGES) -> pad slot

typedef unsigned long long ull;
typedef unsigned short ushort;
typedef __attribute__((ext_vector_type(8))) short short8;   // 8 bf16 (4 VGPRs)
typedef __attribute__((ext_vector_type(4))) float f32x4;    // MFMA C/D

__device__ __forceinline__ ushort rne_bf16(float x) {
    unsigned u = __float_as_uint(x);
    return (ushort)((u + 0x7fffu + ((u >> 16) & 1u)) >> 16);
}
__device__ __forceinline__ float bf2f(ushort u) {
    return __uint_as_float((unsigned)u << 16);
}

// ---------------------------------------------------------------- pass A
// Per-tile LDS histogram; write PADDED counts (roundup8) to histT[tile][bucket].
__global__ __launch_bounds__(1024) void hist_pass(const int* __restrict__ rows,
                                                  int* __restrict__ histT) {
    __shared__ int h[NBUCKET];
    int tid = threadIdx.x, tile = blockIdx.x;
    for (int i = tid; i < NBUCKET; i += 1024) h[i] = 0;
    __syncthreads();
    int base = tile * TILE_EDGES;
#pragma unroll
    for (int i = 0; i < 8; i++) {
        int e = base + i * 1024 + tid;
        if (e < N_EDGES) atomicAdd(&h[rows[e] >> BUCKET_SHIFT], 1);
    }
    __syncthreads();
    for (int i = tid; i < NBUCKET; i += 1024)
        histT[tile * NBUCKET + i] = (h[i] + 7) & ~7;
}

// ---------------------------------------------------------------- transpose
__global__ __launch_bounds__(1024) void transpose_int(const int* __restrict__ in,
                                                      int* __restrict__ out,
                                                      int R, int C) {
    __shared__ int tile[32][33];
    int tx = threadIdx.x, ty = threadIdx.y;
    int r = blockIdx.y * 32 + ty, c = blockIdx.x * 32 + tx;
    if (r < R && c < C) tile[ty][tx] = in[r * C + c];
    __syncthreads();
    int rr = blockIdx.y * 32 + tx, cc = blockIdx.x * 32 + ty;
    if (cc < C && rr < R) out[cc * R + rr] = tile[tx][ty];
}

// ---------------------------------------------------------------- scan
__global__ __launch_bounds__(256) void scan_blocks(const int* __restrict__ in,
                                                   int* __restrict__ out,
                                                   int* __restrict__ blk, int n) {
    __shared__ int sdata[256];
    int t = threadIdx.x;
    int base = blockIdx.x * 1024 + t * 4;
    int v[4];
#pragma unroll
    for (int i = 0; i < 4; i++) {
        int idx = base + i;
        v[i] = (idx < n) ? in[idx] : 0;
    }
    int s = v[0] + v[1] + v[2] + v[3];
    sdata[t] = s;
    __syncthreads();
    for (int off = 1; off < 256; off <<= 1) {
        int x = (t >= off) ? sdata[t - off] : 0;
        __syncthreads();
        sdata[t] += x;
        __syncthreads();
    }
    int excl = sdata[t] - s;
#pragma unroll
    for (int i = 0; i < 4; i++) {
        int idx = base + i;
        if (idx < n) { out[idx] = excl; excl += v[i]; }
    }
    if (t == 255) blk[blockIdx.x] = sdata[255];
}

__global__ __launch_bounds__(256) void scan_add(int* __restrict__ data,
                                                const int* __restrict__ blk, int n) {
    int i = blockIdx.x * 256 + threadIdx.x;
    if (i < n) data[i] += blk[i >> 10];
}

// ---------------------------------------------------------------- pass B
// Re-read rows only; LDS cursors = PADDED offsets; write 4 B records
// (rowLocal<<24 | edgeIdx). Pad slots = 0xFFFFFFFF. Runs 64 B-aligned.
__global__ __launch_bounds__(1024) void scatter_pass(const int* __restrict__ rows,
                                                     const int* __restrict__ cursorT,
                                                     unsigned* __restrict__ etmp4) {
    __shared__ int cur[NBUCKET];
    int tid = threadIdx.x, tile = blockIdx.x;
    for (int i = tid; i < NBUCKET; i += 1024) cur[i] = cursorT[tile * NBUCKET + i];
    __syncthreads();
    int base = tile * TILE_EDGES;
#pragma unroll
    for (int i = 0; i < 8; i++) {
        int e = base + i * 1024 + tid;
        if (e < N_EDGES) {
            int r = rows[e];
            int b = r >> BUCKET_SHIFT;
            int pos = atomicAdd(&cur[b], 1);      // LDS atomic, block-local
            etmp4[pos] = ((unsigned)(r & (BUCKET_ROWS - 1)) << 24) | (unsigned)e;
        }
    }
    __syncthreads();
    for (int i = tid; i < NBUCKET; i += 1024) {
        int c = cur[i];
        int ce = (c + 7) & ~7;
        for (int j = c; j < ce; j++) etmp4[j] = SENT4;
    }
}

// ---------------------------------------------------------------- pass C
// One 512-thr block per 256-row bucket: counting-sort the bucket's padded
// region by local row; gather cols[idx]/vals[idx] (tile-ordered -> ~seq
// windows); emit row_start/row_end + packed edges (val<<32|col); zero-fill
// the tail gap so all slots in [0,EPAD) are finite and inert.
__global__ __launch_bounds__(512) void bucket_sort(const int* __restrict__ histL,
                                                   const int* __restrict__ histC,
                                                   const unsigned* __restrict__ etmp4,
                                                   const int* __restrict__ cols,
                                                   const float* __restrict__ vals,
                                                   ull* __restrict__ edges,
                                                   int* __restrict__ row_start,
                                                   int* __restrict__ row_end) {
    __shared__ int rcnt[BUCKET_ROWS];
    __shared__ int roff[BUCKET_ROWS];
    __shared__ int rcur[BUCKET_ROWS];
    int b = blockIdx.x, t = threadIdx.x;
    int s = histL[b * NTILES];
    int e = (b + 1 < NBUCKET) ? histL[(b + 1) * NTILES]
                              : histL[NH - 1] + histC[NH - 1];
    if (t < BUCKET_ROWS) rcnt[t] = 0;
    __syncthreads();
    for (int j = s + t; j < e; j += 512) {
        unsigned pk = etmp4[j];
        if ((pk & 0xFFFFFFu) != 0xFFFFFFu)
            atomicAdd(&rcnt[pk >> 24], 1);
    }
    __syncthreads();
    if (t < BUCKET_ROWS) roff[t] = rcnt[t];
    __syncthreads();
    for (int off = 1; off < BUCKET_ROWS; off <<= 1) {
        int x = (t >= off && t < BUCKET_ROWS) ? roff[t - off] : 0;
        __syncthreads();
        if (t < BUCKET_ROWS) roff[t] += x;
        __syncthreads();
    }
    if (t < BUCKET_ROWS) {
        int excl = roff[t] - rcnt[t];
        rcur[t] = s + excl;
        int grow = b * BUCKET_ROWS + t;
        if (grow < N_NODES) {
            row_start[grow] = s + excl;
            row_end[grow]   = s + excl + rcnt[t];
        }
    }
    __syncthreads();
    for (int j = s + t; j < e; j += 512) {
        unsigned pk = etmp4[j];
        if ((pk & 0xFFFFFFu) == 0xFFFFFFu) continue;
        int rl = (int)(pk >> 24);
        int idx = (int)(pk & 0xFFFFFFu);
        int pos = atomicAdd(&rcur[rl], 1);        // LDS atomic
        edges[pos] = ((ull)__float_as_uint(vals[idx]) << 32) | (unsigned)cols[idx];
    }
    __syncthreads();
    int realtot = roff[BUCKET_ROWS - 1];
    for (int j = s + realtot + t; j < e; j += 512) edges[j] = 0ull;
}

// ------------------------------------------------------------------- GEMM
// MFMA bf16: H[M,64] = X[M,K] @ W[64,K]^T + b, output bf16. X read once.
template <int K, typename XT>
__global__ __launch_bounds__(256) void gemm_mfma(const XT* __restrict__ X,
                                                 const float* __restrict__ W,
                                                 const float* __restrict__ B,
                                                 ushort* __restrict__ H) {
    constexpr int KS = K / 32;
    int wave = threadIdx.x >> 6;
    int lane = threadIdx.x & 63;
    int quad = lane >> 4;
    int l16  = lane & 15;
    int rowBase = blockIdx.x * 64 + wave * 16;
    int arow = rowBase + l16;
    if (arow > N_NODES - 1) arow = N_NODES - 1;   // clamp OOB loads (stores guarded)

    short8 a[KS];
#pragma unroll
    for (int ks = 0; ks < KS; ks++) {
        int k = ks * 32 + quad * 8;
        if constexpr (sizeof(XT) == 2) {
            a[ks] = *reinterpret_cast<const short8*>(X + (size_t)arow * K + k);
        } else {
            const float4* src = reinterpret_cast<const float4*>(X + (size_t)arow * K + k);
            float4 t0 = src[0], t1 = src[1];
            union { short8 v; ushort u[8]; } cv;
            cv.u[0] = rne_bf16(t0.x); cv.u[1] = rne_bf16(t0.y);
            cv.u[2] = rne_bf16(t0.z); cv.u[3] = rne_bf16(t0.w);
            cv.u[4] = rne_bf16(t1.x); cv.u[5] = rne_bf16(t1.y);
            cv.u[6] = rne_bf16(t1.z); cv.u[7] = rne_bf16(t1.w);
            a[ks] = cv.v;
        }
    }

    f32x4 acc[4];
#pragma unroll
    for (int nt = 0; nt < 4; nt++) acc[nt] = 0.f;

#pragma unroll
    for (int nt = 0; nt < 4; nt++) {
        int brow = nt * 16 + l16;                 // W row = output channel n
#pragma unroll
        for (int ks = 0; ks < KS; ks++) {
            int k = ks * 32 + quad * 8;
            const float4* src = reinterpret_cast<const float4*>(W + brow * K + k);
            float4 t0 = src[0], t1 = src[1];
            union { short8 v; ushort u[8]; } cv;
            cv.u[0] = rne_bf16(t0.x); cv.u[1] = rne_bf16(t0.y);
            cv.u[2] = rne_bf16(t0.z); cv.u[3] = rne_bf16(t0.w);
            cv.u[4] = rne_bf16(t1.x); cv.u[5] = rne_bf16(t1.y);
            cv.u[6] = rne_bf16(t1.z); cv.u[7] = rne_bf16(t1.w);
            acc[nt] = __builtin_amdgcn_mfma_f32_16x16x32_bf16(a[ks], cv.v, acc[nt], 0, 0, 0);
        }
    }

#pragma unroll
    for (int nt = 0; nt < 4; nt++) {
        int n = nt * 16 + l16;
        float bv = B[n];
#pragma unroll
        for (int reg = 0; reg < 4; reg++) {
            int m = rowBase + quad * 4 + reg;
            if (m < N_NODES) H[(size_t)m * HID + n] = rne_bf16(acc[nt][reg] + bv);
        }
    }
}

// ------------------------------------------------------------------- SpMM
// Row-per-wave, WAVE-UNIFORM edges (scalar s_loads — the R10 lesson), but
// each vector gather serves TWO edges: lanes 0-31 fetch edge i's row as
// 32 uints (2 bf16 feats/lane), lanes 32-63 fetch edge i+1's. One cndmask
// per pair selects the scalar base. Halves combined via shfl_xor(32).
// Halves gather-instruction count at equal bytes/lines.
__global__ __launch_bounds__(256) void spmm_relu(const int* __restrict__ row_start,
                                                 const int* __restrict__ row_end,
                                                 const ull* __restrict__ edges,
                                                 const ushort* __restrict__ Hin,
                                                 ushort* __restrict__ Xout) {
    int wid  = (blockIdx.x * 256 + threadIdx.x) >> 6;
    int lane = threadIdx.x & 63;
    if (wid >= N_NODES) return;
    int r = __builtin_amdgcn_readfirstlane(wid);  // wave-uniform -> s_loads
    int start = row_start[r];
    int end   = row_end[r];
    const unsigned* Hu = reinterpret_cast<const unsigned*>(Hin);  // 32 uints/row
    int l = lane & 31;
    bool hi = lane >= 32;
    float acc0 = 0.f, acc1 = 0.f;
    int e = start;
    for (; e + 16 <= end; e += 16) {          // 16 edges = 8 gathers
        ull p[16];
#pragma unroll
        for (int i = 0; i < 16; i++) p[i] = edges[e + i];
        unsigned hv[8];
#pragma unroll
        for (int i = 0; i < 8; i++) {
            int c0 = (int)(unsigned)(p[2 * i]     & 0xFFFFFFFFull);
            int c1 = (int)(unsigned)(p[2 * i + 1] & 0xFFFFFFFFull);
            int c  = hi ? c1 : c0;
            hv[i] = Hu[(size_t)c * 32 + l];
        }
#pragma unroll
        for (int i = 0; i < 8; i++) {
            float v0 = __uint_as_float((unsigned)(p[2 * i]     >> 32));
            float v1 = __uint_as_float((unsigned)(p[2 * i + 1] >> 32));
            float v = hi ? v1 : v0;
            acc0 += v * __uint_as_float(hv[i] << 16);
            acc1 += v * __uint_as_float(hv[i] & 0xFFFF0000u);
        }
    }
    for (; e + 2 <= end; e += 2) {            // paired tail, 1 gather
        ull p0 = edges[e], p1 = edges[e + 1];
        int c = hi ? (int)(unsigned)(p1 & 0xFFFFFFFFull)
                   : (int)(unsigned)(p0 & 0xFFFFFFFFull);
        unsigned hv = Hu[(size_t)c * 32 + l];
        float v = hi ? __uint_as_float((unsigned)(p1 >> 32))
                     : __uint_as_float((unsigned)(p0 >> 32));
        acc0 += v * __uint_as_float(hv << 16);
        acc1 += v * __uint_as_float(hv & 0xFFFF0000u);
    }
    if (e < end) {                            // final odd edge: low half only
        ull p = edges[e];
        int c = (int)(unsigned)(p & 0xFFFFFFFFull);
        unsigned hv = Hu[(size_t)c * 32 + l];
        float v = hi ? 0.f : __uint_as_float((unsigned)(p >> 32));
        acc0 += v * __uint_as_float(hv << 16);
        acc1 += v * __uint_as_float(hv & 0xFFFF0000u);
    }
    acc0 += __shfl_xor(acc0, 32);
    acc1 += __shfl_xor(acc1, 32);
    if (!hi) {
        unsigned res = ((unsigned)rne_bf16(fmaxf(acc1, 0.f)) << 16)
                     |  (unsigned)rne_bf16(fmaxf(acc0, 0.f));
        reinterpret_cast<unsigned*>(Xout)[(size_t)r * 32 + l] = res;
    }
}

// ------------------------------------------------------------------- Pool
// Segmented pool over X1+X2+X3 (bf16): lane = feature; batch sorted ->
// one atomicAdd per segment per wave.
__global__ __launch_bounds__(256) void pool_fused(const ushort* __restrict__ X1,
                                                  const ushort* __restrict__ X2,
                                                  const ushort* __restrict__ X3,
                                                  const int* __restrict__ batch,
                                                  float* __restrict__ sums) {
    int lane = threadIdx.x & 63;
    int w = threadIdx.x >> 6;
    int n0 = blockIdx.x * 128 + w * 32;
    if (n0 >= N_NODES) return;
    int n1 = n0 + 32;
    if (n1 > N_NODES) n1 = N_NODES;
    int g_cur = __builtin_amdgcn_readfirstlane(batch[n0]);
    float acc = 0.f;
    for (int n = n0; n < n1; n++) {
        int g = __builtin_amdgcn_readfirstlane(batch[n]);
        if (g != g_cur) {
            atomicAdd(&sums[g_cur * HID + lane], acc);
            acc = 0.f; g_cur = g;
        }
        size_t base = (size_t)n * HID + lane;
        acc += bf2f(X1[base]) + bf2f(X2[base]) + bf2f(X3[base]);
    }
    atomicAdd(&sums[g_cur * HID + lane], acc);
}

// ------------------------------------------------------------------- Head
__global__ __launch_bounds__(64) void head_kernel(const float* __restrict__ sums,
                                                  const int* __restrict__ batch,
                                                  const float* __restrict__ Wout,
                                                  const float* __restrict__ bout,
                                                  float* __restrict__ out) {
    int g = blockIdx.x;
    int t = threadIdx.x;
    __shared__ float pr[HID];
    __shared__ float lg[OUT_DIM];
    __shared__ float mx, sm;
    auto lb = [&](int key) {
        int lo = 0, hi = N_NODES;
        while (lo < hi) {
            int mid = (lo + hi) >> 1;
            if (batch[mid] < key) lo = mid + 1; else hi = mid;
        }
        return lo;
    };
    int cnt = lb(g + 1) - lb(g);
    float denom = 3.0f * (float)(cnt > 1 ? cnt : 1);
    pr[t] = sums[g * HID + t] / denom;
    __syncthreads();
    if (t < OUT_DIM) {
        float a = bout[t];
        for (int k = 0; k < HID; k++) a += pr[k] * Wout[t * HID + k];
        lg[t] = a;
    }
    __syncthreads();
    if (t == 0) {
        float m = lg[0];
        for (int j = 1; j < OUT_DIM; j++) m = fmaxf(m, lg[j]);
        float s = 0.f;
        for (int j = 0; j < OUT_DIM; j++) s += expf(lg[j] - m);
        mx = m; sm = s;
    }
    __syncthreads();
    if (t < OUT_DIM) out[g * OUT_DIM + t] = expf(lg[t] - mx) / sm;
}

// ---------------------------------------------------------------- launcher
extern "C" void kernel_launch(void* const* d_in, const int* in_sizes, int n_in,
                              void* d_out, int out_size, void* d_ws, size_t ws_size,
                              hipStream_t stream) {
    const float* X    = (const float*)d_in[0];
    const float* vals = (const float*)d_in[1];
    const float* W1   = (const float*)d_in[2];
    const float* b1   = (const float*)d_in[3];
    const float* W2   = (const float*)d_in[4];
    const float* b2   = (const float*)d_in[5];
    const float* W3   = (const float*)d_in[6];
    const float* b3   = (const float*)d_in[7];
    const float* Wout = (const float*)d_in[8];
    const float* bout = (const float*)d_in[9];
    const int*   rows = (const int*)d_in[10];
    const int*   cols = (const int*)d_in[11];
    const int*   batch= (const int*)d_in[12];
    float* out = (float*)d_out;

    char* p = (char*)d_ws;
    auto carve = [&](size_t bytes) {
        void* q = (void*)p;
        p += (bytes + 255) & ~(size_t)255;
        return q;
    };
    ushort* h     = (ushort*)carve((size_t)N_NODES * HID * 2);
    // region A: etmp4 (13.7 MB) before spmm; X1+X2 (25.6 MB) after.
    char*  regA   = (char*) carve((size_t)N_NODES * HID * 4);
    ull*   edges  = (ull*)  carve((size_t)EPAD * 8);        // 27.2 MB
    ushort* X3    = (ushort*)carve((size_t)N_NODES * HID * 2);
    int*   bufA   = (int*)  carve((size_t)NH * 4);   // histT / cursorT [tile][bucket]
    int*   bufB   = (int*)  carve((size_t)NH * 4);   // scanned offsets [bucket][tile]
    int*   bufC   = (int*)  carve((size_t)NH * 4);   // padded counts [bucket][tile]
    int*   row_start = (int*)carve((size_t)N_NODES * 4);
    int*   row_end   = (int*)carve((size_t)N_NODES * 4);
    int*   blkA   = (int*)  carve(1024 * 4);
    int*   blkB   = (int*)  carve(1024 * 4);
    float* sums   = (float*)carve(N_GRAPHS * HID * 4);
    unsigned* etmp4 = (unsigned*)regA;             // dead after bucket_sort
    ushort* X1 = (ushort*)regA;
    ushort* X2 = X1 + (size_t)N_NODES * HID;
    (void)ws_size; (void)in_sizes; (void)n_in; (void)out_size;

    // ---- build: padded hist[tile][bucket] -> transpose -> scan ->
    //      transpose back -> aligned 4 B scatter -> per-bucket sort
    hist_pass<<<NTILES, 1024, 0, stream>>>(rows, bufA);
    transpose_int<<<dim3((NBUCKET + 31) / 32, (NTILES + 31) / 32), dim3(32, 32), 0, stream>>>(bufA, bufC, NTILES, NBUCKET);
    scan_blocks<<<NSCAN1, 256, 0, stream>>>(bufC, bufB, blkA, NH);
    scan_blocks<<<1, 256, 0, stream>>>(blkA, blkA, blkB, NSCAN1);
    scan_add<<<(NH + 255) / 256, 256, 0, stream>>>(bufB, blkA, NH);
    transpose_int<<<dim3((NTILES + 31) / 32, (NBUCKET + 31) / 32), dim3(32, 32), 0, stream>>>(bufB, bufA, NBUCKET, NTILES);
    scatter_pass<<<NTILES, 1024, 0, stream>>>(rows, bufA, etmp4);
    bucket_sort<<<NBUCKET, 512, 0, stream>>>(bufB, bufC, etmp4, cols, vals,
                                             edges, row_start, row_end);

    const int gemm_grid = (N_NODES + 63) / 64;   // 64 rows/block
    const int spmm_grid = (N_NODES + 3) / 4;     // 1 row/wave, 4 waves/block

    // ---- layers (X_l kept separately; pooling sums them later)
    gemm_mfma<IN_DIM, float><<<gemm_grid, 256, 0, stream>>>(X, W1, b1, h);
    spmm_relu<<<spmm_grid, 256, 0, stream>>>(row_start, row_end, edges, h, X1);
    gemm_mfma<HID, ushort><<<gemm_grid, 256, 0, stream>>>(X1, W2, b2, h);
    spmm_relu<<<spmm_grid, 256, 0, stream>>>(row_start, row_end, edges, h, X2);
    gemm_mfma<HID, ushort><<<gemm_grid, 256, 0, stream>>>(X2, W3, b3, h);
    spmm_relu<<<spmm_grid, 256, 0, stream>>>(row_start, row_end, edges, h, X3);

    // ---- pool + head
    hipMemsetAsync(sums, 0, N_GRAPHS * HID * 4, stream);
    pool_fused<<<(N_NODES + 127) / 128, 256, 0, stream>>>(X1, X2, X3, batch, sums);
    head_kernel<<<N_GRAPHS, 64, 0, stream>>>(sums, batch, Wout, bout, out);
}